// Round 12
// baseline (384.208 us; speedup 1.0000x reference)
//
#include <hip/hip_runtime.h>

typedef unsigned short u16;
typedef u16 u16x8 __attribute__((ext_vector_type(8)));
typedef __bf16 bf16x8 __attribute__((ext_vector_type(8)));
typedef __bf16 bf16x2 __attribute__((ext_vector_type(2)));
typedef float f32x4 __attribute__((ext_vector_type(4)));

__device__ __forceinline__ float b2f(u16 h) {
  union { unsigned u; float f; } x; x.u = ((unsigned)h) << 16; return x.f;
}
__device__ __forceinline__ u16 f2b(float f) {
  union { float f; unsigned u; } x; x.f = f;
  unsigned r = x.u + 0x7FFFu + ((x.u >> 16) & 1u);
  return (u16)(r >> 16);
}
__device__ __forceinline__ f32x4 mfma16(bf16x8 a, bf16x8 b, f32x4 c) {
  return __builtin_amdgcn_mfma_f32_16x16x32_bf16(a, b, c, 0, 0, 0);
}
__device__ __forceinline__ void gload16(const void* g, void* l) {
  __builtin_amdgcn_global_load_lds(
      (const __attribute__((address_space(1))) void*)g,
      (__attribute__((address_space(3))) void*)l, 16, 0, 0);
}
#define WAITV4 asm volatile("s_waitcnt vmcnt(4)" ::: "memory")
#define WAITV0 asm volatile("s_waitcnt vmcnt(0)" ::: "memory")
#define WAITL0 asm volatile("s_waitcnt lgkmcnt(0)" ::: "memory")
#define BARRIER asm volatile("s_barrier" ::: "memory")

// ---------------- conversions ------------------------------------------------
__global__ __launch_bounds__(256) void xcvt_k(const float* __restrict__ x0,
                                              const float* __restrict__ x1,
                                              u16* __restrict__ out) {
  int b = blockIdx.x;
  const float* src = (b < 4096) ? x0 : x1;
  u16* dst = out + (b < 4096 ? 0 : 4194304);
  int i = (b & 4095) * 1024 + threadIdx.x * 4;
  float4 v = *(const float4*)&src[i];
  dst[i + 0] = f2b(v.x); dst[i + 1] = f2b(v.y);
  dst[i + 2] = f2b(v.z); dst[i + 3] = f2b(v.w);
}

// weight offsets (u16): wq 0 (merged 1536x512 with wkv), wj1 786432,
// wj2 1310720, wci0 1572864, wci1 2359296, wp 3145728,
// wcoT0 3407872, wcoT1 3670016, Wfin0 3932160, Wfin1 4456448 ([512][1024])
__global__ __launch_bounds__(256) void wcvt_k(
    const float* __restrict__ wq, const float* __restrict__ wkv,
    const float* __restrict__ wj1, const float* __restrict__ wj2,
    const float* __restrict__ wci0, const float* __restrict__ wci1,
    const float* __restrict__ wp, u16* __restrict__ wsb) {
  int b = blockIdx.x; const float* src; size_t doff; int lb;
  if      (b < 256)  { src = wq;   doff = 0;       lb = b; }
  else if (b < 768)  { src = wkv;  doff = 262144;  lb = b - 256; }
  else if (b < 1280) { src = wj1;  doff = 786432;  lb = b - 768; }
  else if (b < 1536) { src = wj2;  doff = 1310720; lb = b - 1280; }
  else if (b < 2304) { src = wci0; doff = 1572864; lb = b - 1536; }
  else if (b < 3072) { src = wci1; doff = 2359296; lb = b - 2304; }
  else               { src = wp;   doff = 3145728; lb = b - 3072; }
  int i = lb * 1024 + threadIdx.x * 4;
  float4 v = *(const float4*)&src[i];
  u16* dst = wsb + doff + i;
  u16 c0 = f2b(v.x), c1 = f2b(v.y), c2 = f2b(v.z), c3 = f2b(v.w);
  dst[0] = c0; dst[1] = c1; dst[2] = c2; dst[3] = c3;
  if (b >= 3072) {  // Wp also into Wfin0/Wfin1 cols 0-511 (row stride 1024)
    int row = i >> 9, col = i & 511;
    u16* f0 = wsb + 3932160 + (size_t)row * 1024 + col;
    u16* f1 = wsb + 4456448 + (size_t)row * 1024 + col;
    f0[0] = c0; f0[1] = c1; f0[2] = c2; f0[3] = c3;
    f1[0] = c0; f1[1] = c1; f1[2] = c2; f1[3] = c3;
  }
}

// transpose-convert Wco_s (f32 [512][512]) -> bf16 [512][512]^T
__global__ __launch_bounds__(256) void tcvt_k(const float* __restrict__ w0,
                                              const float* __restrict__ w1,
                                              u16* __restrict__ o0,
                                              u16* __restrict__ o1) {
  __shared__ u16 t[64][65];
  const int b = blockIdx.x;           // 128: 64 tiles x 2 mats
  const float* src = (b & 64) ? w1 : w0;
  u16* dst = (b & 64) ? o1 : o0;
  const int r0 = ((b >> 3) & 7) * 64, c0 = (b & 7) * 64;
  const int tid = threadIdx.x;
#pragma unroll
  for (int i = 0; i < 16; i++) {
    int idx = tid + i * 256;
    int r = idx >> 6, c = idx & 63;
    t[r][c] = f2b(src[(size_t)(r0 + r) * 512 + c0 + c]);
  }
  __syncthreads();
#pragma unroll
  for (int i = 0; i < 16; i++) {
    int idx = tid + i * 256;
    int c = idx >> 6, r = idx & 63;
    dst[(size_t)(c0 + c) * 512 + r0 + r] = t[r][c];
  }
}

// cvec[0..1023]=kn_s@kw_s^T, [1024..2047]=vn_s@vw_s^T, [2048..3071]=bp+Wp@bco_s
__global__ __launch_bounds__(256) void cvec_k(
    const float* __restrict__ kn, const float* __restrict__ vn,
    const float* __restrict__ bp, const float* __restrict__ bco0,
    const float* __restrict__ bco1, const u16* __restrict__ wci0,
    const u16* __restrict__ wci1, const u16* __restrict__ wp,
    float* __restrict__ out) {
  int idx = blockIdx.x * 256 + threadIdx.x;  // 3072
  int which = idx >> 9, col = idx & 511;
  const float* src; const u16* w; float acc;
  if (which < 4) {
    int s = which & 1, isv = which >> 1;
    src = (isv ? vn : kn) + s * 512;
    w = (s ? wci1 : wci0) + (isv ? 524288 : 262144) + (size_t)col * 512;
    acc = 0.f;
  } else {
    int s = which & 1;
    src = s ? bco1 : bco0;
    w = wp + (size_t)col * 512;
    acc = bp[col];
  }
  for (int k = 0; k < 512; k += 8) {
    u16x8 w8 = *(const u16x8*)&w[k];
#pragma unroll
    for (int j = 0; j < 8; j++) acc += src[k + j] * b2f(w8[j]);
  }
  out[idx] = acc;
}

// ---------------- GEMM v9 (= round-7 gemm4, proven best): 512 thr, ----------
// 128x128 tile, 8 waves (4Mx2N), acc[2][4], 32KB dbuf LDS, counted vmcnt(4)
// out[M][N=ncol*128] = A[M][K]@W[N][K]^T (+epilogue)
// EPI: 0 bf16, 1 bf16 gelu(+bias), 3 f32
// AMODE: 0 plain, 3 concat(A cols<K1 | A[row^8192]),
//        4 cross (col>=1536: A rows ^8192, W rows -512)
template<int EPI, int AMODE>
__global__ __launch_bounds__(512, 4) void gemm9_k(
    const u16* __restrict__ A, int astr, int K1, int K,
    const u16* __restrict__ W0, const u16* __restrict__ W1,
    const float* __restrict__ b0, const float* __restrict__ b1,
    void* __restrict__ outp, int ostr, int ncol) {
  __shared__ u16 SM[32768];   // A(buf) @ buf*16384, W(buf) @ buf*16384+8192
  const int tid = threadIdx.x;
  const int lane = tid & 63;
  const int wv = tid >> 6;
  const int wr = wv >> 1, wc = wv & 1;
  const int lr = lane & 15, lg = lane >> 4;
  const int L = blockIdx.x;
  const int nrow = gridDim.x / ncol;
  int row_b, col_b;
  if ((nrow & 7) == 0) {
    int xcd = L & 7, s = L >> 3;
    row_b = xcd * (nrow >> 3) + s / ncol;
    col_b = s % ncol;
  } else { row_b = L % nrow; col_b = L / nrow; }
  const int row0 = row_b * 128, col0 = col_b * 128;
  const int strm = (row0 >= 8192) ? 1 : 0;
  const u16* W = strm ? W1 : W0;
  const float* bias = strm ? b1 : b0;
  const int shift = (AMODE == 4 && col0 >= 1536) ? 512 : 0;
  const int cxor  = (AMODE == 4 && col0 >= 1536) ? 8192 : 0;
  const int rL = tid >> 3;
  const int bcl = (lane & 7) * 16;

  f32x4 acc[2][4];
#pragma unroll
  for (int m = 0; m < 2; m++)
#pragma unroll
    for (int n = 0; n < 4; n++) acc[m][n] = f32x4{0.f, 0.f, 0.f, 0.f};

  const int nk = K >> 6;

  auto stage = [&](int k0, int buf) {
    const int Ab = buf * 16384, Wb = buf * 16384 + 8192;
#pragma unroll
    for (int ch = 0; ch < 2; ch++) {
      int r = ch * 64 + rL;
      int bcs = bcl ^ ((r & 7) << 4);
      const char* asrc;
      if constexpr (AMODE == 3) {
        if (k0 < K1)
          asrc = (const char*)(A + (size_t)(row0 + r) * astr) + k0 * 2 + bcs;
        else
          asrc = (const char*)(A + (size_t)((row0 + r) ^ 8192) * astr) +
                 (k0 - K1) * 2 + bcs;
      } else {
        asrc = (const char*)(A + (size_t)((row0 + r) ^ cxor) * astr) +
               k0 * 2 + bcs;
      }
      gload16(asrc, &SM[Ab + (ch * 64 + wv * 8) * 64]);
      const char* wsrc =
          (const char*)(W + (size_t)(col0 - shift + r) * K) + k0 * 2 + bcs;
      gload16(wsrc, &SM[Wb + (ch * 64 + wv * 8) * 64]);
    }
  };

  stage(0, 0);
  for (int t = 0; t < nk; t++) {
    const int buf = t & 1;
    if (t + 1 < nk) {
      stage((t + 1) * 64, buf ^ 1);
      WAITV4;
    } else {
      WAITV0;
    }
    BARRIER;
    const int Ab = buf * 16384, Wb = buf * 16384 + 8192;
#pragma unroll
    for (int kk = 0; kk < 2; kk++) {
      const int c = kk * 32 + lg * 8;
      bf16x8 af[2], wf[4];
#pragma unroll
      for (int m = 0; m < 2; m++) {
        int r = wr * 32 + m * 16 + lr;
        af[m] = *(const bf16x8*)&SM[Ab + r * 64 + (c ^ ((r & 7) << 3))];
      }
#pragma unroll
      for (int n = 0; n < 4; n++) {
        int r = wc * 64 + n * 16 + lr;
        wf[n] = *(const bf16x8*)&SM[Wb + r * 64 + (c ^ ((r & 7) << 3))];
      }
#pragma unroll
      for (int m = 0; m < 2; m++)
#pragma unroll
        for (int n = 0; n < 4; n++)
          acc[m][n] = mfma16(af[m], wf[n], acc[m][n]);
    }
    WAITL0;
    BARRIER;
  }

#pragma unroll
  for (int m = 0; m < 2; m++)
#pragma unroll
    for (int n = 0; n < 4; n++)
#pragma unroll
      for (int r = 0; r < 4; r++) {
        int grow = row0 + wr * 32 + m * 16 + lg * 4 + r;
        int gcol = col0 + wc * 64 + n * 16 + lr;
        float v = acc[m][n][r];
        if (bias) v += bias[gcol - shift];
        if (EPI == 1) v = 0.5f * v * (1.0f + erff(v * 0.70710678118f));
        if (EPI == 3) ((float*)outp)[(size_t)grow * ostr + gcol] = v;
        else          ((u16*)outp)[(size_t)grow * ostr + gcol] = f2b(v);
      }
}

// ---------------- V transpose (k-permuted for packed-P PV) -------------------
__global__ __launch_bounds__(256) void vtrans_k(const u16* __restrict__ QKV,
                                                u16* __restrict__ VT) {
  __shared__ u16 t[64][66];
  const int tid = threadIdx.x;
  const int bh = blockIdx.y;  // s*64 + b*8 + h
  const int sb = bh >> 3, h = bh & 7;
  const int n0 = blockIdx.x * 64;
#pragma unroll
  for (int i = 0; i < 16; i++) {
    int idx = tid + i * 256;
    int r = idx >> 6, c = idx & 63;
    t[r][c] = QKV[((size_t)sb * 1024 + n0 + r) * 1536 + 1024 + h * 64 + c];
  }
  __syncthreads();
#pragma unroll
  for (int i = 0; i < 16; i++) {
    int idx = tid + i * 256;
    int r = idx >> 6, p = idx & 63;
    int tok = ((p >> 5) << 5) + ((p & 31) >> 1) + ((p & 1) << 4);
    VT[((size_t)bh * 64 + r) * 1024 + n0 + p] = t[tok][r];
  }
}

// ---------------- fused self-attention: BARRIER-FREE, K/V gathered from L2 ---
// LDS holds only Pt (wave-private rows) -> no __syncthreads in whole kernel.
// XCD swizzle keeps each bh's K/V (256KB) L2-resident across its 8 q-blocks.
// writes y into OC[t][0:512] with row stride 1024
__global__ __launch_bounds__(256) void attn_k(const u16* __restrict__ QKV,
                                              const u16* __restrict__ VT,
                                              u16* __restrict__ OC) {
  __shared__ u16 Pt[128 * 64];   // 16KB
  const int STR = 1536;
  const int tid = threadIdx.x, lane = tid & 63, wv = tid >> 6;
  const int lr = lane & 15, lg = lane >> 4;
  const int L = blockIdx.x;
  const int by = L & 127;        // s*64 + b*8 + h ; L%8 = bh%8 -> same XCD
  const int q0 = (L >> 7) * 128;
  const int sb = by >> 3, h = by & 7;
  const size_t rowbase = (size_t)sb * 1024;
  const float SC = 0.18033688f;  // 0.125 * log2(e)

  bf16x8 qa[2][2];
#pragma unroll
  for (int m = 0; m < 2; m++)
#pragma unroll
    for (int kk = 0; kk < 2; kk++) {
      int r = q0 + wv * 32 + m * 16 + lr;
      int c = h * 64 + kk * 32 + lg * 8;
      qa[m][kk] = *(const bf16x8*)&QKV[(rowbase + r) * STR + c];
    }

  f32x4 o[2][4];
#pragma unroll
  for (int m = 0; m < 2; m++)
#pragma unroll
    for (int n = 0; n < 4; n++) o[m][n] = f32x4{0.f, 0.f, 0.f, 0.f};
  float ls[2][4] = {{0.f, 0.f, 0.f, 0.f}, {0.f, 0.f, 0.f, 0.f}};

  for (int t = 0; t < 16; t++) {
    const int c0 = t * 64;
    // QK^T: K fragments gathered straight from global (L2-hot)
    f32x4 s[2][4];
#pragma unroll
    for (int m = 0; m < 2; m++)
#pragma unroll
      for (int n = 0; n < 4; n++) s[m][n] = f32x4{0.f, 0.f, 0.f, 0.f};
#pragma unroll
    for (int kk = 0; kk < 2; kk++) {
      const int c = kk * 32 + lg * 8;
      bf16x8 kf[4];
#pragma unroll
      for (int n = 0; n < 4; n++) {
        kf[n] = *(const bf16x8*)&QKV[(rowbase + c0 + n * 16 + lr) * STR +
                                     512 + h * 64 + c];
      }
#pragma unroll
      for (int m = 0; m < 2; m++)
#pragma unroll
        for (int n = 0; n < 4; n++) s[m][n] = mfma16(qa[m][kk], kf[n], s[m][n]);
    }
    // P = exp2(S*SC); pack col pairs (c, c+16) as u32 at permuted position
#pragma unroll
    for (int m = 0; m < 2; m++)
#pragma unroll
      for (int r = 0; r < 4; r++) {
        int prow = wv * 32 + m * 16 + lg * 4 + r;
        float p00 = __builtin_amdgcn_exp2f(s[m][0][r] * SC);
        float p01 = __builtin_amdgcn_exp2f(s[m][1][r] * SC);
        float p10 = __builtin_amdgcn_exp2f(s[m][2][r] * SC);
        float p11 = __builtin_amdgcn_exp2f(s[m][3][r] * SC);
        ls[m][r] += (p00 + p01) + (p10 + p11);
        bf16x2 w0; w0[0] = (__bf16)p00; w0[1] = (__bf16)p01;
        bf16x2 w1; w1[0] = (__bf16)p10; w1[1] = (__bf16)p11;
        int ib = prow * 64, xr = (prow & 7) << 3;
        *(bf16x2*)&Pt[ib + ((lr * 2) ^ xr)] = w0;
        *(bf16x2*)&Pt[ib + ((32 + lr * 2) ^ xr)] = w1;
      }
    // PV: V^T fragments gathered from global (permutation baked into VT)
#pragma unroll
    for (int kc = 0; kc < 2; kc++) {
      const int cc = kc * 32 + lg * 8;
      bf16x8 pa[2], vf[4];
#pragma unroll
      for (int m = 0; m < 2; m++) {
        int r = wv * 32 + m * 16 + lr;
        pa[m] = *(const bf16x8*)&Pt[r * 64 + (cc ^ ((r & 7) << 3))];
      }
#pragma unroll
      for (int n = 0; n < 4; n++) {
        vf[n] = *(const bf16x8*)&VT[((size_t)by * 64 + n * 16 + lr) * 1024 +
                                    c0 + cc];
      }
#pragma unroll
      for (int m = 0; m < 2; m++)
#pragma unroll
        for (int n = 0; n < 4; n++) o[m][n] = mfma16(pa[m], vf[n], o[m][n]);
    }
  }

#pragma unroll
  for (int m = 0; m < 2; m++)
#pragma unroll
    for (int r = 0; r < 4; r++) {
      float v = ls[m][r];
      v += __shfl_xor(v, 1); v += __shfl_xor(v, 2);
      v += __shfl_xor(v, 4); v += __shfl_xor(v, 8);
      ls[m][r] = v;
    }
#pragma unroll
  for (int m = 0; m < 2; m++)
#pragma unroll
    for (int n = 0; n < 4; n++)
#pragma unroll
      for (int r = 0; r < 4; r++) {
        int grow = q0 + wv * 32 + m * 16 + lg * 4 + r;
        int gcol = h * 64 + n * 16 + lr;
        OC[(rowbase + grow) * 1024 + gcol] = f2b(o[m][n][r] / ls[m][r]);
      }
}

// ---------------- fused judger softmax + multiply: ykr = y * softmax(logits) -
__global__ __launch_bounds__(256) void relmul_k(const u16* __restrict__ RL,
                                                const u16* __restrict__ OC,
                                                u16* __restrict__ YKR) {
  const int row = blockIdx.x * 4 + (threadIdx.x >> 6);
  const int lane = threadIdx.x & 63;
  u16x8 lv = *(const u16x8*)&RL[(size_t)row * 512 + lane * 8];
  float e[8]; float s = 0.f;
#pragma unroll
  for (int j = 0; j < 8; j++) { e[j] = __expf(b2f(lv[j])); s += e[j]; }
  for (int x = 1; x < 64; x <<= 1) s += __shfl_xor(s, x);
  float inv = 1.0f / s;
  u16x8 y8 = *(const u16x8*)&OC[(size_t)row * 1024 + lane * 8];
  u16x8 o8;
#pragma unroll
  for (int j = 0; j < 8; j++) o8[j] = f2b(b2f(y8[j]) * (e[j] * inv));
  *(u16x8*)&YKR[(size_t)row * 512 + lane * 8] = o8;
}

// ---------------- 2-key cross attention: one wave per token ------------------
// writes o into OC[t][512:1024] (row stride 1024)
__global__ __launch_bounds__(256) void twokey3_k(const u16* __restrict__ CP,
                                                 const u16* __restrict__ KP1,
                                                 const float* __restrict__ cvec,
                                                 u16* __restrict__ OC) {
  const int t = blockIdx.x * 4 + (threadIdx.x >> 6);
  const int lane = threadIdx.x & 63;
  const int s = t >> 13;
  const size_t rb = (size_t)t * 2048 + lane * 8;
  u16x8 q8 = *(const u16x8*)&CP[rb];
  u16x8 a8 = *(const u16x8*)&CP[rb + 512];
  u16x8 v0 = *(const u16x8*)&CP[rb + 1024];
  u16x8 v1 = *(const u16x8*)&CP[rb + 1536];
  u16x8 b8 = *(const u16x8*)&KP1[(size_t)t * 512 + lane * 8];
  const float* ck = cvec + s * 512 + lane * 8;
  const float* cv = cvec + 1024 + s * 512 + lane * 8;

  float s0 = 0.f, s1 = 0.f;
#pragma unroll
  for (int j = 0; j < 8; j++) {
    float qf = b2f(q8[j]);
    s0 += qf * (b2f(a8[j]) + ck[j]);
    s1 += qf * b2f(b8[j]);
  }
  s0 += __shfl_xor(s0, 1); s1 += __shfl_xor(s1, 1);
  s0 += __shfl_xor(s0, 2); s1 += __shfl_xor(s1, 2);
  s0 += __shfl_xor(s0, 4); s1 += __shfl_xor(s1, 4);

  float e0 = __expf(s0 * 0.125f), e1 = __expf(s1 * 0.125f);
  float rr = 1.0f / (e0 + e1);
  float w0 = e0 * rr, w1 = e1 * rr;
  u16x8 o8;
#pragma unroll
  for (int j = 0; j < 8; j++)
    o8[j] = f2b(w0 * (b2f(v0[j]) + cv[j]) + w1 * b2f(v1[j]));
  *(u16x8*)&OC[(size_t)t * 1024 + 512 + lane * 8] = o8;
}

// =============================================================================
extern "C" void kernel_launch(void* const* d_in, const int* in_sizes, int n_in,
                              void* d_out, int out_size, void* d_ws, size_t ws_size,
                              hipStream_t stream) {
  (void)in_sizes; (void)n_in; (void)out_size; (void)ws_size;
  const float* x0  = (const float*)d_in[0];
  const float* x1  = (const float*)d_in[1];
  const float* Wq  = (const float*)d_in[4];
  const float* Wkv = (const float*)d_in[5];
  const float* Wj1 = (const float*)d_in[6];
  const float* bj1 = (const float*)d_in[7];
  const float* Wj2 = (const float*)d_in[8];
  const float* bj2 = (const float*)d_in[9];
  const float* kn  = (const float*)d_in[10];
  const float* vn  = (const float*)d_in[11];
  const float* Wci[2]  = {(const float*)d_in[12], (const float*)d_in[16]};
  const float* bci[2]  = {(const float*)d_in[13], (const float*)d_in[17]};
  const float* Wco[2]  = {(const float*)d_in[14], (const float*)d_in[18]};
  const float* bco[2]  = {(const float*)d_in[15], (const float*)d_in[19]};
  const float* Wp  = (const float*)d_in[20];
  const float* bp  = (const float*)d_in[21];

  u16* wsb = (u16*)d_ws;
  u16* wqb   = wsb;                 // merged [1536][512]
  u16* wj1b  = wsb + 786432;
  u16* wj2b  = wsb + 1310720;
  u16* wcib[2] = {wsb + 1572864, wsb + 2359296};
  u16* wpb   = wsb + 3145728;
  u16* wcoT[2] = {wsb + 3407872, wsb + 3670016};
  u16* wfin[2] = {wsb + 3932160, wsb + 4456448};  // [512][1024]
  float* cvecb = (float*)(wsb + 4980736);          // 3072 floats
  const size_t SLOT = 8388608;                     // 16 MB in u16
  u16* base = wsb + 5242880;
  u16* S0 = base;                // x -> HID -> KP1
  u16* OC = base + 1 * SLOT;     // [16384][1024]: y | o  (2 slots)
  u16* S3 = base + 3 * SLOT;     // QKV(S3..S5) -> REL -> CP(S3..S6)
  u16* S4 = base + 4 * SLOT;     // ... -> YKR
  u16* S6 = base + 6 * SLOT;     // VT
  u16* QKV = S3;
  u16* REL = S3;
  u16* CP  = S3;
  u16* YKR = S4;

  dim3 blk(256), gblk(512);
  xcvt_k<<<dim3(8192), blk, 0, stream>>>(x0, x1, S0);
  wcvt_k<<<dim3(3328), blk, 0, stream>>>(Wq, Wkv, Wj1, Wj2, Wci[0], Wci[1],
                                         Wp, wsb);
  tcvt_k<<<dim3(128), blk, 0, stream>>>(Wco[0], Wco[1], wcoT[0], wcoT[1]);
  cvec_k<<<dim3(12), blk, 0, stream>>>(kn, vn, bp, bco[0], bco[1],
                                       wcib[0], wcib[1], wpb, cvecb);
  // Wcomb_s = Wp @ Wco_s -> Wfin_s cols 512-1023
  for (int s = 0; s < 2; s++)
    gemm9_k<0, 0><<<dim3(16), gblk, 0, stream>>>(
        wpb, 512, 512, 512, wcoT[s], wcoT[s], nullptr, nullptr,
        wfin[s] + 512, 1024, 4);

  // qkv projection: [16384][512] @ [1536][512]^T -> QKV
  gemm9_k<0, 0><<<dim3(1536), gblk, 0, stream>>>(
      S0, 512, 512, 512, wqb, wqb, nullptr, nullptr, QKV, 1536, 12);
  vtrans_k<<<dim3(16, 128), blk, 0, stream>>>(QKV, S6);
  attn_k<<<dim3(1024), blk, 0, stream>>>(QKV, S6, OC);   // y -> OC[:,0:512]

  // judger: HID = gelu([y_s|y_other] @ Wj1^T + bj1) -> S0 (x dead)
  gemm9_k<1, 3><<<dim3(512), gblk, 0, stream>>>(
      OC, 1024, 512, 1024, wj1b, wj1b, bj1, bj1, S0, 512, 4);
  // REL logits = HID @ Wj2^T + bj2 -> S3 (QKV dead)
  gemm9_k<0, 0><<<dim3(512), gblk, 0, stream>>>(
      S0, 512, 512, 512, wj2b, wj2b, bj2, bj2, REL, 512, 4);
  // ykr = y * softmax(REL) -> S4
  relmul_k<<<dim3(4096), blk, 0, stream>>>(REL, OC, YKR);
  // kp1 = ykr @ kw^T + bk -> S0 (HID dead)
  gemm9_k<0, 0><<<dim3(512), gblk, 0, stream>>>(
      YKR, 512, 512, 512, wcib[0] + 262144, wcib[1] + 262144,
      bci[0] + 512, bci[1] + 512, S0, 512, 4);
  // merged cross projection -> CP [16384][2048] (4th block: y_other @ vw_s)
  gemm9_k<0, 4><<<dim3(2048), gblk, 0, stream>>>(
      OC, 1024, 512, 512, wcib[0], wcib[1], bci[0], bci[1], CP, 2048, 16);

  twokey3_k<<<dim3(4096), blk, 0, stream>>>(CP, S0, cvecb, OC);

  // out = [y|o] @ [Wp | Wp@Wco_s]^T + bcomb_s  (f32)
  gemm9_k<3, 0><<<dim3(512), gblk, 0, stream>>>(
      OC, 1024, 1024, 1024, wfin[0], wfin[1], cvecb + 2048, cvecb + 2560,
      d_out, 512, 4);
}

// Round 13
// 320.958 us; speedup vs baseline: 1.1971x; 1.1971x over previous
//
#include <hip/hip_runtime.h>

typedef unsigned short u16;
typedef u16 u16x8 __attribute__((ext_vector_type(8)));
typedef __bf16 bf16x8 __attribute__((ext_vector_type(8)));
typedef __bf16 bf16x2 __attribute__((ext_vector_type(2)));
typedef float f32x4 __attribute__((ext_vector_type(4)));

__device__ __forceinline__ float b2f(u16 h) {
  union { unsigned u; float f; } x; x.u = ((unsigned)h) << 16; return x.f;
}
__device__ __forceinline__ u16 f2b(float f) {
  union { float f; unsigned u; } x; x.f = f;
  unsigned r = x.u + 0x7FFFu + ((x.u >> 16) & 1u);
  return (u16)(r >> 16);
}
__device__ __forceinline__ f32x4 mfma16(bf16x8 a, bf16x8 b, f32x4 c) {
  return __builtin_amdgcn_mfma_f32_16x16x32_bf16(a, b, c, 0, 0, 0);
}
__device__ __forceinline__ void gload16(const void* g, void* l) {
  __builtin_amdgcn_global_load_lds(
      (const __attribute__((address_space(1))) void*)g,
      (__attribute__((address_space(3))) void*)l, 16, 0, 0);
}
#define WAITV4 asm volatile("s_waitcnt vmcnt(4)" ::: "memory")
#define WAITV0 asm volatile("s_waitcnt vmcnt(0)" ::: "memory")
#define WAITL0 asm volatile("s_waitcnt lgkmcnt(0)" ::: "memory")
#define BARRIER asm volatile("s_barrier" ::: "memory")

// ---------------- conversions ------------------------------------------------
__global__ __launch_bounds__(256) void xcvt_k(const float* __restrict__ x0,
                                              const float* __restrict__ x1,
                                              u16* __restrict__ out) {
  int b = blockIdx.x;
  const float* src = (b < 4096) ? x0 : x1;
  u16* dst = out + (b < 4096 ? 0 : 4194304);
  int i = (b & 4095) * 1024 + threadIdx.x * 4;
  float4 v = *(const float4*)&src[i];
  dst[i + 0] = f2b(v.x); dst[i + 1] = f2b(v.y);
  dst[i + 2] = f2b(v.z); dst[i + 3] = f2b(v.w);
}

// weight offsets (u16): wq 0 (merged 1536x512 with wkv), wj1 786432,
// wj2 1310720, wci0 1572864, wci1 2359296, wp 3145728,
// wcoT0 3407872, wcoT1 3670016, Wfin0 3932160, Wfin1 4456448 ([512][1024])
__global__ __launch_bounds__(256) void wcvt_k(
    const float* __restrict__ wq, const float* __restrict__ wkv,
    const float* __restrict__ wj1, const float* __restrict__ wj2,
    const float* __restrict__ wci0, const float* __restrict__ wci1,
    const float* __restrict__ wp, u16* __restrict__ wsb) {
  int b = blockIdx.x; const float* src; size_t doff; int lb;
  if      (b < 256)  { src = wq;   doff = 0;       lb = b; }
  else if (b < 768)  { src = wkv;  doff = 262144;  lb = b - 256; }
  else if (b < 1280) { src = wj1;  doff = 786432;  lb = b - 768; }
  else if (b < 1536) { src = wj2;  doff = 1310720; lb = b - 1280; }
  else if (b < 2304) { src = wci0; doff = 1572864; lb = b - 1536; }
  else if (b < 3072) { src = wci1; doff = 2359296; lb = b - 2304; }
  else               { src = wp;   doff = 3145728; lb = b - 3072; }
  int i = lb * 1024 + threadIdx.x * 4;
  float4 v = *(const float4*)&src[i];
  u16* dst = wsb + doff + i;
  u16 c0 = f2b(v.x), c1 = f2b(v.y), c2 = f2b(v.z), c3 = f2b(v.w);
  dst[0] = c0; dst[1] = c1; dst[2] = c2; dst[3] = c3;
  if (b >= 3072) {  // Wp also into Wfin0/Wfin1 cols 0-511 (row stride 1024)
    int row = i >> 9, col = i & 511;
    u16* f0 = wsb + 3932160 + (size_t)row * 1024 + col;
    u16* f1 = wsb + 4456448 + (size_t)row * 1024 + col;
    f0[0] = c0; f0[1] = c1; f0[2] = c2; f0[3] = c3;
    f1[0] = c0; f1[1] = c1; f1[2] = c2; f1[3] = c3;
  }
}

// transpose-convert Wco_s (f32 [512][512]) -> bf16 [512][512]^T
__global__ __launch_bounds__(256) void tcvt_k(const float* __restrict__ w0,
                                              const float* __restrict__ w1,
                                              u16* __restrict__ o0,
                                              u16* __restrict__ o1) {
  __shared__ u16 t[64][65];
  const int b = blockIdx.x;           // 128: 64 tiles x 2 mats
  const float* src = (b & 64) ? w1 : w0;
  u16* dst = (b & 64) ? o1 : o0;
  const int r0 = ((b >> 3) & 7) * 64, c0 = (b & 7) * 64;
  const int tid = threadIdx.x;
#pragma unroll
  for (int i = 0; i < 16; i++) {
    int idx = tid + i * 256;
    int r = idx >> 6, c = idx & 63;
    t[r][c] = f2b(src[(size_t)(r0 + r) * 512 + c0 + c]);
  }
  __syncthreads();
#pragma unroll
  for (int i = 0; i < 16; i++) {
    int idx = tid + i * 256;
    int c = idx >> 6, r = idx & 63;
    dst[(size_t)(c0 + c) * 512 + r0 + r] = t[r][c];
  }
}

// cvec[0..1023]=kn_s@kw_s^T, [1024..2047]=vn_s@vw_s^T, [2048..3071]=bp+Wp@bco_s
__global__ __launch_bounds__(256) void cvec_k(
    const float* __restrict__ kn, const float* __restrict__ vn,
    const float* __restrict__ bp, const float* __restrict__ bco0,
    const float* __restrict__ bco1, const u16* __restrict__ wci0,
    const u16* __restrict__ wci1, const u16* __restrict__ wp,
    float* __restrict__ out) {
  int idx = blockIdx.x * 256 + threadIdx.x;  // 3072
  int which = idx >> 9, col = idx & 511;
  const float* src; const u16* w; float acc;
  if (which < 4) {
    int s = which & 1, isv = which >> 1;
    src = (isv ? vn : kn) + s * 512;
    w = (s ? wci1 : wci0) + (isv ? 524288 : 262144) + (size_t)col * 512;
    acc = 0.f;
  } else {
    int s = which & 1;
    src = s ? bco1 : bco0;
    w = wp + (size_t)col * 512;
    acc = bp[col];
  }
  for (int k = 0; k < 512; k += 8) {
    u16x8 w8 = *(const u16x8*)&w[k];
#pragma unroll
    for (int j = 0; j < 8; j++) acc += src[k + j] * b2f(w8[j]);
  }
  out[idx] = acc;
}

// ---------------- GEMM v9 (round-7 structure, best measured): 512 thr, ------
// 128x128 tile, 8 waves (4Mx2N), acc[2][4], 32KB dbuf LDS, counted vmcnt(4)
// out[M][N=ncol*128] = A[M][K]@W[N][K]^T (+epilogue)
// EPI: 0 bf16, 1 bf16 gelu(+bias), 3 f32
// AMODE: 0 plain, 3 concat(A cols<K1 | A[row^8192]),
//        4 cross (col>=1536: A rows ^8192, W rows -512)
template<int EPI, int AMODE>
__global__ __launch_bounds__(512, 4) void gemm9_k(
    const u16* __restrict__ A, int astr, int K1, int K,
    const u16* __restrict__ W0, const u16* __restrict__ W1,
    const float* __restrict__ b0, const float* __restrict__ b1,
    void* __restrict__ outp, int ostr, int ncol) {
  __shared__ u16 SM[32768];   // A(buf) @ buf*16384, W(buf) @ buf*16384+8192
  const int tid = threadIdx.x;
  const int lane = tid & 63;
  const int wv = tid >> 6;
  const int wr = wv >> 1, wc = wv & 1;
  const int lr = lane & 15, lg = lane >> 4;
  const int L = blockIdx.x;
  const int nrow = gridDim.x / ncol;
  int row_b, col_b;
  if ((nrow & 7) == 0) {
    int xcd = L & 7, s = L >> 3;
    row_b = xcd * (nrow >> 3) + s / ncol;
    col_b = s % ncol;
  } else { row_b = L % nrow; col_b = L / nrow; }
  const int row0 = row_b * 128, col0 = col_b * 128;
  const int strm = (row0 >= 8192) ? 1 : 0;
  const u16* W = strm ? W1 : W0;
  const float* bias = strm ? b1 : b0;
  const int shift = (AMODE == 4 && col0 >= 1536) ? 512 : 0;
  const int cxor  = (AMODE == 4 && col0 >= 1536) ? 8192 : 0;
  const int rL = tid >> 3;
  const int bcl = (lane & 7) * 16;

  f32x4 acc[2][4];
#pragma unroll
  for (int m = 0; m < 2; m++)
#pragma unroll
    for (int n = 0; n < 4; n++) acc[m][n] = f32x4{0.f, 0.f, 0.f, 0.f};

  const int nk = K >> 6;

  auto stage = [&](int k0, int buf) {
    const int Ab = buf * 16384, Wb = buf * 16384 + 8192;
#pragma unroll
    for (int ch = 0; ch < 2; ch++) {
      int r = ch * 64 + rL;
      int bcs = bcl ^ ((r & 7) << 4);
      const char* asrc;
      if constexpr (AMODE == 3) {
        if (k0 < K1)
          asrc = (const char*)(A + (size_t)(row0 + r) * astr) + k0 * 2 + bcs;
        else
          asrc = (const char*)(A + (size_t)((row0 + r) ^ 8192) * astr) +
                 (k0 - K1) * 2 + bcs;
      } else {
        asrc = (const char*)(A + (size_t)((row0 + r) ^ cxor) * astr) +
               k0 * 2 + bcs;
      }
      gload16(asrc, &SM[Ab + (ch * 64 + wv * 8) * 64]);
      const char* wsrc =
          (const char*)(W + (size_t)(col0 - shift + r) * K) + k0 * 2 + bcs;
      gload16(wsrc, &SM[Wb + (ch * 64 + wv * 8) * 64]);
    }
  };

  stage(0, 0);
  for (int t = 0; t < nk; t++) {
    const int buf = t & 1;
    if (t + 1 < nk) {
      stage((t + 1) * 64, buf ^ 1);
      WAITV4;
    } else {
      WAITV0;
    }
    BARRIER;
    const int Ab = buf * 16384, Wb = buf * 16384 + 8192;
#pragma unroll
    for (int kk = 0; kk < 2; kk++) {
      const int c = kk * 32 + lg * 8;
      bf16x8 af[2], wf[4];
#pragma unroll
      for (int m = 0; m < 2; m++) {
        int r = wr * 32 + m * 16 + lr;
        af[m] = *(const bf16x8*)&SM[Ab + r * 64 + (c ^ ((r & 7) << 3))];
      }
#pragma unroll
      for (int n = 0; n < 4; n++) {
        int r = wc * 64 + n * 16 + lr;
        wf[n] = *(const bf16x8*)&SM[Wb + r * 64 + (c ^ ((r & 7) << 3))];
      }
#pragma unroll
      for (int m = 0; m < 2; m++)
#pragma unroll
        for (int n = 0; n < 4; n++)
          acc[m][n] = mfma16(af[m], wf[n], acc[m][n]);
    }
    WAITL0;
    BARRIER;
  }

#pragma unroll
  for (int m = 0; m < 2; m++)
#pragma unroll
    for (int n = 0; n < 4; n++)
#pragma unroll
      for (int r = 0; r < 4; r++) {
        int grow = row0 + wr * 32 + m * 16 + lg * 4 + r;
        int gcol = col0 + wc * 64 + n * 16 + lr;
        float v = acc[m][n][r];
        if (bias) v += bias[gcol - shift];
        if (EPI == 1) v = 0.5f * v * (1.0f + erff(v * 0.70710678118f));
        if (EPI == 3) ((float*)outp)[(size_t)grow * ostr + gcol] = v;
        else          ((u16*)outp)[(size_t)grow * ostr + gcol] = f2b(v);
      }
}

// ---------------- V transpose (k-permuted for packed-P PV) -------------------
__global__ __launch_bounds__(256) void vtrans_k(const u16* __restrict__ QKV,
                                                u16* __restrict__ VT) {
  __shared__ u16 t[64][66];
  const int tid = threadIdx.x;
  const int bh = blockIdx.y;  // s*64 + b*8 + h
  const int sb = bh >> 3, h = bh & 7;
  const int n0 = blockIdx.x * 64;
#pragma unroll
  for (int i = 0; i < 16; i++) {
    int idx = tid + i * 256;
    int r = idx >> 6, c = idx & 63;
    t[r][c] = QKV[((size_t)sb * 1024 + n0 + r) * 1536 + 1024 + h * 64 + c];
  }
  __syncthreads();
#pragma unroll
  for (int i = 0; i < 16; i++) {
    int idx = tid + i * 256;
    int r = idx >> 6, p = idx & 63;
    int tok = ((p >> 5) << 5) + ((p & 31) >> 1) + ((p & 1) << 4);
    VT[((size_t)bh * 64 + r) * 1024 + n0 + p] = t[tok][r];
  }
}

// ---------------- fused self-attention (round-11 structure + setprio) --------
// writes y into OC[t][0:512] with row stride 1024
__global__ __launch_bounds__(256) void attn_k(const u16* __restrict__ QKV,
                                              const u16* __restrict__ VT,
                                              u16* __restrict__ OC) {
  __shared__ u16 SM[24576];  // K(buf)@buf*8192, V@+4096, Pt@16384
  const int STR = 1536;
  const int tid = threadIdx.x, lane = tid & 63, wv = tid >> 6;
  const int lr = lane & 15, lg = lane >> 4;
  const int L = blockIdx.x;
  const int by = L & 127;
  const int q0 = (L >> 7) * 128;
  const int sb = by >> 3, h = by & 7;
  const size_t rowbase = (size_t)sb * 1024;
  const int bcl = (lane & 7) * 16;
  const float SC = 0.18033688f;

  bf16x8 qa[2][2];
#pragma unroll
  for (int m = 0; m < 2; m++)
#pragma unroll
    for (int kk = 0; kk < 2; kk++) {
      int r = q0 + wv * 32 + m * 16 + lr;
      int c = h * 64 + kk * 32 + lg * 8;
      qa[m][kk] = *(const bf16x8*)&QKV[(rowbase + r) * STR + c];
    }

  f32x4 o[2][4];
#pragma unroll
  for (int m = 0; m < 2; m++)
#pragma unroll
    for (int n = 0; n < 4; n++) o[m][n] = f32x4{0.f, 0.f, 0.f, 0.f};
  float ls[2][4] = {{0.f, 0.f, 0.f, 0.f}, {0.f, 0.f, 0.f, 0.f}};

  auto stagekv = [&](int c0, int buf) {
#pragma unroll
    for (int ch = 0; ch < 2; ch++) {
      int r = ch * 32 + (tid >> 3);
      int bcs = bcl ^ ((r & 7) << 4);
      const char* ks =
          (const char*)(QKV + (rowbase + c0 + r) * STR + 512 + h * 64) + bcs;
      gload16(ks, &SM[buf * 8192 + (ch * 32 + wv * 8) * 64]);
      const char* vs =
          (const char*)(VT + ((size_t)by * 64 + r) * 1024 + c0) + bcs;
      gload16(vs, &SM[buf * 8192 + 4096 + (ch * 32 + wv * 8) * 64]);
    }
  };

  stagekv(0, 0);
  for (int t = 0; t < 16; t++) {
    const int buf = t & 1;
    if (t < 15) {
      stagekv((t + 1) * 64, buf ^ 1);
      WAITV4;
    } else {
      WAITV0;
    }
    BARRIER;
    const int Kb = buf * 8192, Vb = buf * 8192 + 4096;

    f32x4 s[2][4];
#pragma unroll
    for (int m = 0; m < 2; m++)
#pragma unroll
      for (int n = 0; n < 4; n++) s[m][n] = f32x4{0.f, 0.f, 0.f, 0.f};
    __builtin_amdgcn_s_setprio(1);
#pragma unroll
    for (int kk = 0; kk < 2; kk++) {
      const int c = kk * 32 + lg * 8;
      bf16x8 kf[4];
#pragma unroll
      for (int n = 0; n < 4; n++) {
        int r = n * 16 + lr;
        kf[n] = *(const bf16x8*)&SM[Kb + r * 64 + (c ^ ((r & 7) << 3))];
      }
#pragma unroll
      for (int m = 0; m < 2; m++)
#pragma unroll
        for (int n = 0; n < 4; n++) s[m][n] = mfma16(qa[m][kk], kf[n], s[m][n]);
    }
    __builtin_amdgcn_s_setprio(0);
#pragma unroll
    for (int m = 0; m < 2; m++)
#pragma unroll
      for (int r = 0; r < 4; r++) {
        int prow = wv * 32 + m * 16 + lg * 4 + r;
        float p00 = __builtin_amdgcn_exp2f(s[m][0][r] * SC);
        float p01 = __builtin_amdgcn_exp2f(s[m][1][r] * SC);
        float p10 = __builtin_amdgcn_exp2f(s[m][2][r] * SC);
        float p11 = __builtin_amdgcn_exp2f(s[m][3][r] * SC);
        ls[m][r] += (p00 + p01) + (p10 + p11);
        bf16x2 w0; w0[0] = (__bf16)p00; w0[1] = (__bf16)p01;
        bf16x2 w1; w1[0] = (__bf16)p10; w1[1] = (__bf16)p11;
        int ib = 16384 + prow * 64, xr = (prow & 7) << 3;
        *(bf16x2*)&SM[ib + ((lr * 2) ^ xr)] = w0;
        *(bf16x2*)&SM[ib + ((32 + lr * 2) ^ xr)] = w1;
      }
    __builtin_amdgcn_s_setprio(1);
#pragma unroll
    for (int kc = 0; kc < 2; kc++) {
      const int cc = kc * 32 + lg * 8;
      bf16x8 pa[2], vf[4];
#pragma unroll
      for (int m = 0; m < 2; m++) {
        int r = wv * 32 + m * 16 + lr;
        pa[m] = *(const bf16x8*)&SM[16384 + r * 64 + (cc ^ ((r & 7) << 3))];
      }
#pragma unroll
      for (int n = 0; n < 4; n++) {
        int r = n * 16 + lr;
        vf[n] = *(const bf16x8*)&SM[Vb + r * 64 + (cc ^ ((r & 7) << 3))];
      }
#pragma unroll
      for (int m = 0; m < 2; m++)
#pragma unroll
        for (int n = 0; n < 4; n++) o[m][n] = mfma16(pa[m], vf[n], o[m][n]);
    }
    __builtin_amdgcn_s_setprio(0);
    WAITL0;
    BARRIER;
  }

#pragma unroll
  for (int m = 0; m < 2; m++)
#pragma unroll
    for (int r = 0; r < 4; r++) {
      float v = ls[m][r];
      v += __shfl_xor(v, 1); v += __shfl_xor(v, 2);
      v += __shfl_xor(v, 4); v += __shfl_xor(v, 8);
      ls[m][r] = v;
    }
#pragma unroll
  for (int m = 0; m < 2; m++)
#pragma unroll
    for (int n = 0; n < 4; n++)
#pragma unroll
      for (int r = 0; r < 4; r++) {
        int grow = q0 + wv * 32 + m * 16 + lg * 4 + r;
        int gcol = h * 64 + n * 16 + lr;
        OC[(rowbase + grow) * 1024 + gcol] = f2b(o[m][n][r] / ls[m][r]);
      }
}

// ---------------- fused judger softmax + multiply: ykr = y * softmax(logits) -
__global__ __launch_bounds__(256) void relmul_k(const u16* __restrict__ RL,
                                                const u16* __restrict__ OC,
                                                u16* __restrict__ YKR) {
  const int row = blockIdx.x * 4 + (threadIdx.x >> 6);
  const int lane = threadIdx.x & 63;
  u16x8 lv = *(const u16x8*)&RL[(size_t)row * 512 + lane * 8];
  float e[8]; float s = 0.f;
#pragma unroll
  for (int j = 0; j < 8; j++) { e[j] = __expf(b2f(lv[j])); s += e[j]; }
  for (int x = 1; x < 64; x <<= 1) s += __shfl_xor(s, x);
  float inv = 1.0f / s;
  u16x8 y8 = *(const u16x8*)&OC[(size_t)row * 1024 + lane * 8];
  u16x8 o8;
#pragma unroll
  for (int j = 0; j < 8; j++) o8[j] = f2b(b2f(y8[j]) * (e[j] * inv));
  *(u16x8*)&YKR[(size_t)row * 512 + lane * 8] = o8;
}

// ---------------- 2-key cross attention: one wave per token ------------------
// writes o into OC[t][512:1024] (row stride 1024)
__global__ __launch_bounds__(256) void twokey3_k(const u16* __restrict__ CP,
                                                 const u16* __restrict__ KP1,
                                                 const float* __restrict__ cvec,
                                                 u16* __restrict__ OC) {
  const int t = blockIdx.x * 4 + (threadIdx.x >> 6);
  const int lane = threadIdx.x & 63;
  const int s = t >> 13;
  const size_t rb = (size_t)t * 2048 + lane * 8;
  u16x8 q8 = *(const u16x8*)&CP[rb];
  u16x8 a8 = *(const u16x8*)&CP[rb + 512];
  u16x8 v0 = *(const u16x8*)&CP[rb + 1024];
  u16x8 v1 = *(const u16x8*)&CP[rb + 1536];
  u16x8 b8 = *(const u16x8*)&KP1[(size_t)t * 512 + lane * 8];
  const float* ck = cvec + s * 512 + lane * 8;
  const float* cv = cvec + 1024 + s * 512 + lane * 8;

  float s0 = 0.f, s1 = 0.f;
#pragma unroll
  for (int j = 0; j < 8; j++) {
    float qf = b2f(q8[j]);
    s0 += qf * (b2f(a8[j]) + ck[j]);
    s1 += qf * b2f(b8[j]);
  }
  s0 += __shfl_xor(s0, 1); s1 += __shfl_xor(s1, 1);
  s0 += __shfl_xor(s0, 2); s1 += __shfl_xor(s1, 2);
  s0 += __shfl_xor(s0, 4); s1 += __shfl_xor(s1, 4);

  float e0 = __expf(s0 * 0.125f), e1 = __expf(s1 * 0.125f);
  float rr = 1.0f / (e0 + e1);
  float w0 = e0 * rr, w1 = e1 * rr;
  u16x8 o8;
#pragma unroll
  for (int j = 0; j < 8; j++)
    o8[j] = f2b(w0 * (b2f(v0[j]) + cv[j]) + w1 * b2f(v1[j]));
  *(u16x8*)&OC[(size_t)t * 1024 + 512 + lane * 8] = o8;
}

// =============================================================================
extern "C" void kernel_launch(void* const* d_in, const int* in_sizes, int n_in,
                              void* d_out, int out_size, void* d_ws, size_t ws_size,
                              hipStream_t stream) {
  (void)in_sizes; (void)n_in; (void)out_size; (void)ws_size;
  const float* x0  = (const float*)d_in[0];
  const float* x1  = (const float*)d_in[1];
  const float* Wq  = (const float*)d_in[4];
  const float* Wkv = (const float*)d_in[5];
  const float* Wj1 = (const float*)d_in[6];
  const float* bj1 = (const float*)d_in[7];
  const float* Wj2 = (const float*)d_in[8];
  const float* bj2 = (const float*)d_in[9];
  const float* kn  = (const float*)d_in[10];
  const float* vn  = (const float*)d_in[11];
  const float* Wci[2]  = {(const float*)d_in[12], (const float*)d_in[16]};
  const float* bci[2]  = {(const float*)d_in[13], (const float*)d_in[17]};
  const float* Wco[2]  = {(const float*)d_in[14], (const float*)d_in[18]};
  const float* bco[2]  = {(const float*)d_in[15], (const float*)d_in[19]};
  const float* Wp  = (const float*)d_in[20];
  const float* bp  = (const float*)d_in[21];

  u16* wsb = (u16*)d_ws;
  u16* wqb   = wsb;                 // merged [1536][512]
  u16* wj1b  = wsb + 786432;
  u16* wj2b  = wsb + 1310720;
  u16* wcib[2] = {wsb + 1572864, wsb + 2359296};
  u16* wpb   = wsb + 3145728;
  u16* wcoT[2] = {wsb + 3407872, wsb + 3670016};
  u16* wfin[2] = {wsb + 3932160, wsb + 4456448};  // [512][1024]
  float* cvecb = (float*)(wsb + 4980736);          // 3072 floats
  const size_t SLOT = 8388608;                     // 16 MB in u16
  u16* base = wsb + 5242880;
  u16* S0 = base;                // x -> HID -> KP1
  u16* OC = base + 1 * SLOT;     // [16384][1024]: y | o  (2 slots)
  u16* S3 = base + 3 * SLOT;     // QKV(S3..S5) -> REL -> CP(S3..S6)
  u16* S4 = base + 4 * SLOT;     // ... -> YKR
  u16* S6 = base + 6 * SLOT;     // VT
  u16* QKV = S3;
  u16* REL = S3;
  u16* CP  = S3;
  u16* YKR = S4;

  dim3 blk(256), gblk(512);
  xcvt_k<<<dim3(8192), blk, 0, stream>>>(x0, x1, S0);
  wcvt_k<<<dim3(3328), blk, 0, stream>>>(Wq, Wkv, Wj1, Wj2, Wci[0], Wci[1],
                                         Wp, wsb);
  tcvt_k<<<dim3(128), blk, 0, stream>>>(Wco[0], Wco[1], wcoT[0], wcoT[1]);
  cvec_k<<<dim3(12), blk, 0, stream>>>(kn, vn, bp, bco[0], bco[1],
                                       wcib[0], wcib[1], wpb, cvecb);
  // Wcomb_s = Wp @ Wco_s -> Wfin_s cols 512-1023
  for (int s = 0; s < 2; s++)
    gemm9_k<0, 0><<<dim3(16), gblk, 0, stream>>>(
        wpb, 512, 512, 512, wcoT[s], wcoT[s], nullptr, nullptr,
        wfin[s] + 512, 1024, 4);

  // qkv projection: [16384][512] @ [1536][512]^T -> QKV
  gemm9_k<0, 0><<<dim3(1536), gblk, 0, stream>>>(
      S0, 512, 512, 512, wqb, wqb, nullptr, nullptr, QKV, 1536, 12);
  vtrans_k<<<dim3(16, 128), blk, 0, stream>>>(QKV, S6);
  attn_k<<<dim3(1024), blk, 0, stream>>>(QKV, S6, OC);   // y -> OC[:,0:512]

  // judger: HID = gelu([y_s|y_other] @ Wj1^T + bj1) -> S0 (x dead)
  gemm9_k<1, 3><<<dim3(512), gblk, 0, stream>>>(
      OC, 1024, 512, 1024, wj1b, wj1b, bj1, bj1, S0, 512, 4);
  // REL logits = HID @ Wj2^T + bj2 -> S3 (QKV dead)
  gemm9_k<0, 0><<<dim3(512), gblk, 0, stream>>>(
      S0, 512, 512, 512, wj2b, wj2b, bj2, bj2, REL, 512, 4);
  // ykr = y * softmax(REL) -> S4
  relmul_k<<<dim3(4096), blk, 0, stream>>>(REL, OC, YKR);
  // kp1 = ykr @ kw^T + bk -> S0 (HID dead)
  gemm9_k<0, 0><<<dim3(512), gblk, 0, stream>>>(
      YKR, 512, 512, 512, wcib[0] + 262144, wcib[1] + 262144,
      bci[0] + 512, bci[1] + 512, S0, 512, 4);
  // merged cross projection -> CP [16384][2048] (4th block: y_other @ vw_s)
  gemm9_k<0, 4><<<dim3(2048), gblk, 0, stream>>>(
      OC, 1024, 512, 512, wcib[0], wcib[1], bci[0], bci[1], CP, 2048, 16);

  twokey3_k<<<dim3(4096), blk, 0, stream>>>(CP, S0, cvecb, OC);

  // out = [y|o] @ [Wp | Wp@Wco_s]^T + bcomb_s  (f32)
  gemm9_k<3, 0><<<dim3(512), gblk, 0, stream>>>(
      OC, 1024, 1024, 1024, wfin[0], wfin[1], cvecb + 2048, cvecb + 2560,
      d_out, 512, 4);
}

// Round 14
// 312.469 us; speedup vs baseline: 1.2296x; 1.0272x over previous
//
#include <hip/hip_runtime.h>

typedef unsigned short u16;
typedef u16 u16x8 __attribute__((ext_vector_type(8)));
typedef __bf16 bf16x8 __attribute__((ext_vector_type(8)));
typedef __bf16 bf16x2 __attribute__((ext_vector_type(2)));
typedef float f32x4 __attribute__((ext_vector_type(4)));

__device__ __forceinline__ float b2f(u16 h) {
  union { unsigned u; float f; } x; x.u = ((unsigned)h) << 16; return x.f;
}
__device__ __forceinline__ u16 f2b(float f) {
  union { float f; unsigned u; } x; x.f = f;
  unsigned r = x.u + 0x7FFFu + ((x.u >> 16) & 1u);
  return (u16)(r >> 16);
}
__device__ __forceinline__ f32x4 mfma16(bf16x8 a, bf16x8 b, f32x4 c) {
  return __builtin_amdgcn_mfma_f32_16x16x32_bf16(a, b, c, 0, 0, 0);
}
__device__ __forceinline__ void gload16(const void* g, void* l) {
  __builtin_amdgcn_global_load_lds(
      (const __attribute__((address_space(1))) void*)g,
      (__attribute__((address_space(3))) void*)l, 16, 0, 0);
}
#define WAITV4 asm volatile("s_waitcnt vmcnt(4)" ::: "memory")
#define WAITV0 asm volatile("s_waitcnt vmcnt(0)" ::: "memory")
#define WAITL0 asm volatile("s_waitcnt lgkmcnt(0)" ::: "memory")
#define BARRIER asm volatile("s_barrier" ::: "memory")

// ---------------- conversions ------------------------------------------------
__global__ __launch_bounds__(256) void xcvt_k(const float* __restrict__ x0,
                                              const float* __restrict__ x1,
                                              u16* __restrict__ out) {
  int b = blockIdx.x;
  const float* src = (b < 4096) ? x0 : x1;
  u16* dst = out + (b < 4096 ? 0 : 4194304);
  int i = (b & 4095) * 1024 + threadIdx.x * 4;
  float4 v = *(const float4*)&src[i];
  dst[i + 0] = f2b(v.x); dst[i + 1] = f2b(v.y);
  dst[i + 2] = f2b(v.z); dst[i + 3] = f2b(v.w);
}

// weight offsets (u16): wq 0 (merged 1536x512 with wkv), wj1 786432,
// wj2 1310720, wci0 1572864, wci1 2359296, wp 3145728,
// wcoT0 3407872, wcoT1 3670016, Wfin0 3932160, Wfin1 4456448 ([512][1024])
__global__ __launch_bounds__(256) void wcvt_k(
    const float* __restrict__ wq, const float* __restrict__ wkv,
    const float* __restrict__ wj1, const float* __restrict__ wj2,
    const float* __restrict__ wci0, const float* __restrict__ wci1,
    const float* __restrict__ wp, u16* __restrict__ wsb) {
  int b = blockIdx.x; const float* src; size_t doff; int lb;
  if      (b < 256)  { src = wq;   doff = 0;       lb = b; }
  else if (b < 768)  { src = wkv;  doff = 262144;  lb = b - 256; }
  else if (b < 1280) { src = wj1;  doff = 786432;  lb = b - 768; }
  else if (b < 1536) { src = wj2;  doff = 1310720; lb = b - 1280; }
  else if (b < 2304) { src = wci0; doff = 1572864; lb = b - 1536; }
  else if (b < 3072) { src = wci1; doff = 2359296; lb = b - 2304; }
  else               { src = wp;   doff = 3145728; lb = b - 3072; }
  int i = lb * 1024 + threadIdx.x * 4;
  float4 v = *(const float4*)&src[i];
  u16* dst = wsb + doff + i;
  u16 c0 = f2b(v.x), c1 = f2b(v.y), c2 = f2b(v.z), c3 = f2b(v.w);
  dst[0] = c0; dst[1] = c1; dst[2] = c2; dst[3] = c3;
  if (b >= 3072) {  // Wp also into Wfin0/Wfin1 cols 0-511 (row stride 1024)
    int row = i >> 9, col = i & 511;
    u16* f0 = wsb + 3932160 + (size_t)row * 1024 + col;
    u16* f1 = wsb + 4456448 + (size_t)row * 1024 + col;
    f0[0] = c0; f0[1] = c1; f0[2] = c2; f0[3] = c3;
    f1[0] = c0; f1[1] = c1; f1[2] = c2; f1[3] = c3;
  }
}

// transpose-convert Wco_s (f32 [512][512]) -> bf16 [512][512]^T
__global__ __launch_bounds__(256) void tcvt_k(const float* __restrict__ w0,
                                              const float* __restrict__ w1,
                                              u16* __restrict__ o0,
                                              u16* __restrict__ o1) {
  __shared__ u16 t[64][65];
  const int b = blockIdx.x;           // 128: 64 tiles x 2 mats
  const float* src = (b & 64) ? w1 : w0;
  u16* dst = (b & 64) ? o1 : o0;
  const int r0 = ((b >> 3) & 7) * 64, c0 = (b & 7) * 64;
  const int tid = threadIdx.x;
#pragma unroll
  for (int i = 0; i < 16; i++) {
    int idx = tid + i * 256;
    int r = idx >> 6, c = idx & 63;
    t[r][c] = f2b(src[(size_t)(r0 + r) * 512 + c0 + c]);
  }
  __syncthreads();
#pragma unroll
  for (int i = 0; i < 16; i++) {
    int idx = tid + i * 256;
    int c = idx >> 6, r = idx & 63;
    dst[(size_t)(c0 + c) * 512 + r0 + r] = t[r][c];
  }
}

// cvec[0..1023]=kn_s@kw_s^T, [1024..2047]=vn_s@vw_s^T, [2048..3071]=bp+Wp@bco_s
__global__ __launch_bounds__(256) void cvec_k(
    const float* __restrict__ kn, const float* __restrict__ vn,
    const float* __restrict__ bp, const float* __restrict__ bco0,
    const float* __restrict__ bco1, const u16* __restrict__ wci0,
    const u16* __restrict__ wci1, const u16* __restrict__ wp,
    float* __restrict__ out) {
  int idx = blockIdx.x * 256 + threadIdx.x;  // 3072
  int which = idx >> 9, col = idx & 511;
  const float* src; const u16* w; float acc;
  if (which < 4) {
    int s = which & 1, isv = which >> 1;
    src = (isv ? vn : kn) + s * 512;
    w = (s ? wci1 : wci0) + (isv ? 524288 : 262144) + (size_t)col * 512;
    acc = 0.f;
  } else {
    int s = which & 1;
    src = s ? bco1 : bco0;
    w = wp + (size_t)col * 512;
    acc = bp[col];
  }
  for (int k = 0; k < 512; k += 8) {
    u16x8 w8 = *(const u16x8*)&w[k];
#pragma unroll
    for (int j = 0; j < 8; j++) acc += src[k + j] * b2f(w8[j]);
  }
  out[idx] = acc;
}

// ---------------- GEMM v9 (round-7 structure, best measured): 512 thr, ------
// 128x128 tile, 8 waves (4Mx2N), acc[2][4], 32KB dbuf LDS, counted vmcnt(4)
// out[M][N=ncol*128] = A[M][K]@W[N][K]^T (+epilogue)
// EPI: 0 bf16, 1 bf16 gelu(+bias), 3 f32
// AMODE: 0 plain, 3 concat(A cols<K1 | A[row^8192]),
//        4 cross (col>=1536: A rows ^8192, W rows -512)
template<int EPI, int AMODE>
__global__ __launch_bounds__(512, 4) void gemm9_k(
    const u16* __restrict__ A, int astr, int K1, int K,
    const u16* __restrict__ W0, const u16* __restrict__ W1,
    const float* __restrict__ b0, const float* __restrict__ b1,
    void* __restrict__ outp, int ostr, int ncol) {
  __shared__ u16 SM[32768];   // A(buf) @ buf*16384, W(buf) @ buf*16384+8192
  const int tid = threadIdx.x;
  const int lane = tid & 63;
  const int wv = tid >> 6;
  const int wr = wv >> 1, wc = wv & 1;
  const int lr = lane & 15, lg = lane >> 4;
  const int L = blockIdx.x;
  const int nrow = gridDim.x / ncol;
  int row_b, col_b;
  if ((nrow & 7) == 0) {
    int xcd = L & 7, s = L >> 3;
    row_b = xcd * (nrow >> 3) + s / ncol;
    col_b = s % ncol;
  } else { row_b = L % nrow; col_b = L / nrow; }
  const int row0 = row_b * 128, col0 = col_b * 128;
  const int strm = (row0 >= 8192) ? 1 : 0;
  const u16* W = strm ? W1 : W0;
  const float* bias = strm ? b1 : b0;
  const int shift = (AMODE == 4 && col0 >= 1536) ? 512 : 0;
  const int cxor  = (AMODE == 4 && col0 >= 1536) ? 8192 : 0;
  const int rL = tid >> 3;
  const int bcl = (lane & 7) * 16;

  f32x4 acc[2][4];
#pragma unroll
  for (int m = 0; m < 2; m++)
#pragma unroll
    for (int n = 0; n < 4; n++) acc[m][n] = f32x4{0.f, 0.f, 0.f, 0.f};

  const int nk = K >> 6;

  auto stage = [&](int k0, int buf) {
    const int Ab = buf * 16384, Wb = buf * 16384 + 8192;
#pragma unroll
    for (int ch = 0; ch < 2; ch++) {
      int r = ch * 64 + rL;
      int bcs = bcl ^ ((r & 7) << 4);
      const char* asrc;
      if constexpr (AMODE == 3) {
        if (k0 < K1)
          asrc = (const char*)(A + (size_t)(row0 + r) * astr) + k0 * 2 + bcs;
        else
          asrc = (const char*)(A + (size_t)((row0 + r) ^ 8192) * astr) +
                 (k0 - K1) * 2 + bcs;
      } else {
        asrc = (const char*)(A + (size_t)((row0 + r) ^ cxor) * astr) +
               k0 * 2 + bcs;
      }
      gload16(asrc, &SM[Ab + (ch * 64 + wv * 8) * 64]);
      const char* wsrc =
          (const char*)(W + (size_t)(col0 - shift + r) * K) + k0 * 2 + bcs;
      gload16(wsrc, &SM[Wb + (ch * 64 + wv * 8) * 64]);
    }
  };

  stage(0, 0);
  for (int t = 0; t < nk; t++) {
    const int buf = t & 1;
    if (t + 1 < nk) {
      stage((t + 1) * 64, buf ^ 1);
      WAITV4;
    } else {
      WAITV0;
    }
    BARRIER;
    const int Ab = buf * 16384, Wb = buf * 16384 + 8192;
#pragma unroll
    for (int kk = 0; kk < 2; kk++) {
      const int c = kk * 32 + lg * 8;
      bf16x8 af[2], wf[4];
#pragma unroll
      for (int m = 0; m < 2; m++) {
        int r = wr * 32 + m * 16 + lr;
        af[m] = *(const bf16x8*)&SM[Ab + r * 64 + (c ^ ((r & 7) << 3))];
      }
#pragma unroll
      for (int n = 0; n < 4; n++) {
        int r = wc * 64 + n * 16 + lr;
        wf[n] = *(const bf16x8*)&SM[Wb + r * 64 + (c ^ ((r & 7) << 3))];
      }
#pragma unroll
      for (int m = 0; m < 2; m++)
#pragma unroll
        for (int n = 0; n < 4; n++)
          acc[m][n] = mfma16(af[m], wf[n], acc[m][n]);
    }
    WAITL0;
    BARRIER;
  }

#pragma unroll
  for (int m = 0; m < 2; m++)
#pragma unroll
    for (int n = 0; n < 4; n++)
#pragma unroll
      for (int r = 0; r < 4; r++) {
        int grow = row0 + wr * 32 + m * 16 + lg * 4 + r;
        int gcol = col0 + wc * 64 + n * 16 + lr;
        float v = acc[m][n][r];
        if (bias) v += bias[gcol - shift];
        if (EPI == 1) v = 0.5f * v * (1.0f + erff(v * 0.70710678118f));
        if (EPI == 3) ((float*)outp)[(size_t)grow * ostr + gcol] = v;
        else          ((u16*)outp)[(size_t)grow * ostr + gcol] = f2b(v);
      }
}

// ---------------- V transpose (k-permuted for packed-P PV) -------------------
__global__ __launch_bounds__(256) void vtrans_k(const u16* __restrict__ QKV,
                                                u16* __restrict__ VT) {
  __shared__ u16 t[64][66];
  const int tid = threadIdx.x;
  const int bh = blockIdx.y;  // s*64 + b*8 + h
  const int sb = bh >> 3, h = bh & 7;
  const int n0 = blockIdx.x * 64;
#pragma unroll
  for (int i = 0; i < 16; i++) {
    int idx = tid + i * 256;
    int r = idx >> 6, c = idx & 63;
    t[r][c] = QKV[((size_t)sb * 1024 + n0 + r) * 1536 + 1024 + h * 64 + c];
  }
  __syncthreads();
#pragma unroll
  for (int i = 0; i < 16; i++) {
    int idx = tid + i * 256;
    int r = idx >> 6, p = idx & 63;
    int tok = ((p >> 5) << 5) + ((p & 31) >> 1) + ((p & 1) << 4);
    VT[((size_t)bh * 64 + r) * 1024 + n0 + p] = t[tok][r];
  }
}

// ---------------- fused self-attention (round-11 structure, best measured) ---
// writes y into OC[t][0:512] with row stride 1024
__global__ __launch_bounds__(256) void attn_k(const u16* __restrict__ QKV,
                                              const u16* __restrict__ VT,
                                              u16* __restrict__ OC) {
  __shared__ u16 SM[24576];  // K(buf)@buf*8192, V@+4096, Pt@16384
  const int STR = 1536;
  const int tid = threadIdx.x, lane = tid & 63, wv = tid >> 6;
  const int lr = lane & 15, lg = lane >> 4;
  const int L = blockIdx.x;
  const int by = L & 127;
  const int q0 = (L >> 7) * 128;
  const int sb = by >> 3, h = by & 7;
  const size_t rowbase = (size_t)sb * 1024;
  const int bcl = (lane & 7) * 16;
  const float SC = 0.18033688f;

  bf16x8 qa[2][2];
#pragma unroll
  for (int m = 0; m < 2; m++)
#pragma unroll
    for (int kk = 0; kk < 2; kk++) {
      int r = q0 + wv * 32 + m * 16 + lr;
      int c = h * 64 + kk * 32 + lg * 8;
      qa[m][kk] = *(const bf16x8*)&QKV[(rowbase + r) * STR + c];
    }

  f32x4 o[2][4];
#pragma unroll
  for (int m = 0; m < 2; m++)
#pragma unroll
    for (int n = 0; n < 4; n++) o[m][n] = f32x4{0.f, 0.f, 0.f, 0.f};
  float ls[2][4] = {{0.f, 0.f, 0.f, 0.f}, {0.f, 0.f, 0.f, 0.f}};

  auto stagekv = [&](int c0, int buf) {
#pragma unroll
    for (int ch = 0; ch < 2; ch++) {
      int r = ch * 32 + (tid >> 3);
      int bcs = bcl ^ ((r & 7) << 4);
      const char* ks =
          (const char*)(QKV + (rowbase + c0 + r) * STR + 512 + h * 64) + bcs;
      gload16(ks, &SM[buf * 8192 + (ch * 32 + wv * 8) * 64]);
      const char* vs =
          (const char*)(VT + ((size_t)by * 64 + r) * 1024 + c0) + bcs;
      gload16(vs, &SM[buf * 8192 + 4096 + (ch * 32 + wv * 8) * 64]);
    }
  };

  stagekv(0, 0);
  for (int t = 0; t < 16; t++) {
    const int buf = t & 1;
    if (t < 15) {
      stagekv((t + 1) * 64, buf ^ 1);
      WAITV4;
    } else {
      WAITV0;
    }
    BARRIER;
    const int Kb = buf * 8192, Vb = buf * 8192 + 4096;

    f32x4 s[2][4];
#pragma unroll
    for (int m = 0; m < 2; m++)
#pragma unroll
      for (int n = 0; n < 4; n++) s[m][n] = f32x4{0.f, 0.f, 0.f, 0.f};
#pragma unroll
    for (int kk = 0; kk < 2; kk++) {
      const int c = kk * 32 + lg * 8;
      bf16x8 kf[4];
#pragma unroll
      for (int n = 0; n < 4; n++) {
        int r = n * 16 + lr;
        kf[n] = *(const bf16x8*)&SM[Kb + r * 64 + (c ^ ((r & 7) << 3))];
      }
#pragma unroll
      for (int m = 0; m < 2; m++)
#pragma unroll
        for (int n = 0; n < 4; n++) s[m][n] = mfma16(qa[m][kk], kf[n], s[m][n]);
    }
#pragma unroll
    for (int m = 0; m < 2; m++)
#pragma unroll
      for (int r = 0; r < 4; r++) {
        int prow = wv * 32 + m * 16 + lg * 4 + r;
        float p00 = __builtin_amdgcn_exp2f(s[m][0][r] * SC);
        float p01 = __builtin_amdgcn_exp2f(s[m][1][r] * SC);
        float p10 = __builtin_amdgcn_exp2f(s[m][2][r] * SC);
        float p11 = __builtin_amdgcn_exp2f(s[m][3][r] * SC);
        ls[m][r] += (p00 + p01) + (p10 + p11);
        bf16x2 w0; w0[0] = (__bf16)p00; w0[1] = (__bf16)p01;
        bf16x2 w1; w1[0] = (__bf16)p10; w1[1] = (__bf16)p11;
        int ib = 16384 + prow * 64, xr = (prow & 7) << 3;
        *(bf16x2*)&SM[ib + ((lr * 2) ^ xr)] = w0;
        *(bf16x2*)&SM[ib + ((32 + lr * 2) ^ xr)] = w1;
      }
#pragma unroll
    for (int kc = 0; kc < 2; kc++) {
      const int cc = kc * 32 + lg * 8;
      bf16x8 pa[2], vf[4];
#pragma unroll
      for (int m = 0; m < 2; m++) {
        int r = wv * 32 + m * 16 + lr;
        pa[m] = *(const bf16x8*)&SM[16384 + r * 64 + (cc ^ ((r & 7) << 3))];
      }
#pragma unroll
      for (int n = 0; n < 4; n++) {
        int r = n * 16 + lr;
        vf[n] = *(const bf16x8*)&SM[Vb + r * 64 + (cc ^ ((r & 7) << 3))];
      }
#pragma unroll
      for (int m = 0; m < 2; m++)
#pragma unroll
        for (int n = 0; n < 4; n++) o[m][n] = mfma16(pa[m], vf[n], o[m][n]);
    }
    WAITL0;
    BARRIER;
  }

#pragma unroll
  for (int m = 0; m < 2; m++)
#pragma unroll
    for (int r = 0; r < 4; r++) {
      float v = ls[m][r];
      v += __shfl_xor(v, 1); v += __shfl_xor(v, 2);
      v += __shfl_xor(v, 4); v += __shfl_xor(v, 8);
      ls[m][r] = v;
    }
#pragma unroll
  for (int m = 0; m < 2; m++)
#pragma unroll
    for (int n = 0; n < 4; n++)
#pragma unroll
      for (int r = 0; r < 4; r++) {
        int grow = q0 + wv * 32 + m * 16 + lg * 4 + r;
        int gcol = h * 64 + n * 16 + lr;
        OC[(rowbase + grow) * 1024 + gcol] = f2b(o[m][n][r] / ls[m][r]);
      }
}

// ---------------- fused judger softmax + multiply: ykr = y * softmax(logits) -
__global__ __launch_bounds__(256) void relmul_k(const u16* __restrict__ RL,
                                                const u16* __restrict__ OC,
                                                u16* __restrict__ YKR) {
  const int row = blockIdx.x * 4 + (threadIdx.x >> 6);
  const int lane = threadIdx.x & 63;
  u16x8 lv = *(const u16x8*)&RL[(size_t)row * 512 + lane * 8];
  float e[8]; float s = 0.f;
#pragma unroll
  for (int j = 0; j < 8; j++) { e[j] = __expf(b2f(lv[j])); s += e[j]; }
  for (int x = 1; x < 64; x <<= 1) s += __shfl_xor(s, x);
  float inv = 1.0f / s;
  u16x8 y8 = *(const u16x8*)&OC[(size_t)row * 1024 + lane * 8];
  u16x8 o8;
#pragma unroll
  for (int j = 0; j < 8; j++) o8[j] = f2b(b2f(y8[j]) * (e[j] * inv));
  *(u16x8*)&YKR[(size_t)row * 512 + lane * 8] = o8;
}

// ---------------- 2-key cross attention: one wave per token ------------------
// writes o into OC[t][512:1024] (row stride 1024)
__global__ __launch_bounds__(256) void twokey3_k(const u16* __restrict__ CP,
                                                 const u16* __restrict__ KP1,
                                                 const float* __restrict__ cvec,
                                                 u16* __restrict__ OC) {
  const int t = blockIdx.x * 4 + (threadIdx.x >> 6);
  const int lane = threadIdx.x & 63;
  const int s = t >> 13;
  const size_t rb = (size_t)t * 2048 + lane * 8;
  u16x8 q8 = *(const u16x8*)&CP[rb];
  u16x8 a8 = *(const u16x8*)&CP[rb + 512];
  u16x8 v0 = *(const u16x8*)&CP[rb + 1024];
  u16x8 v1 = *(const u16x8*)&CP[rb + 1536];
  u16x8 b8 = *(const u16x8*)&KP1[(size_t)t * 512 + lane * 8];
  const float* ck = cvec + s * 512 + lane * 8;
  const float* cv = cvec + 1024 + s * 512 + lane * 8;

  float s0 = 0.f, s1 = 0.f;
#pragma unroll
  for (int j = 0; j < 8; j++) {
    float qf = b2f(q8[j]);
    s0 += qf * (b2f(a8[j]) + ck[j]);
    s1 += qf * b2f(b8[j]);
  }
  s0 += __shfl_xor(s0, 1); s1 += __shfl_xor(s1, 1);
  s0 += __shfl_xor(s0, 2); s1 += __shfl_xor(s1, 2);
  s0 += __shfl_xor(s0, 4); s1 += __shfl_xor(s1, 4);

  float e0 = __expf(s0 * 0.125f), e1 = __expf(s1 * 0.125f);
  float rr = 1.0f / (e0 + e1);
  float w0 = e0 * rr, w1 = e1 * rr;
  u16x8 o8;
#pragma unroll
  for (int j = 0; j < 8; j++)
    o8[j] = f2b(w0 * (b2f(v0[j]) + cv[j]) + w1 * b2f(v1[j]));
  *(u16x8*)&OC[(size_t)t * 1024 + 512 + lane * 8] = o8;
}

// =============================================================================
extern "C" void kernel_launch(void* const* d_in, const int* in_sizes, int n_in,
                              void* d_out, int out_size, void* d_ws, size_t ws_size,
                              hipStream_t stream) {
  (void)in_sizes; (void)n_in; (void)out_size; (void)ws_size;
  const float* x0  = (const float*)d_in[0];
  const float* x1  = (const float*)d_in[1];
  const float* Wq  = (const float*)d_in[4];
  const float* Wkv = (const float*)d_in[5];
  const float* Wj1 = (const float*)d_in[6];
  const float* bj1 = (const float*)d_in[7];
  const float* Wj2 = (const float*)d_in[8];
  const float* bj2 = (const float*)d_in[9];
  const float* kn  = (const float*)d_in[10];
  const float* vn  = (const float*)d_in[11];
  const float* Wci[2]  = {(const float*)d_in[12], (const float*)d_in[16]};
  const float* bci[2]  = {(const float*)d_in[13], (const float*)d_in[17]};
  const float* Wco[2]  = {(const float*)d_in[14], (const float*)d_in[18]};
  const float* bco[2]  = {(const float*)d_in[15], (const float*)d_in[19]};
  const float* Wp  = (const float*)d_in[20];
  const float* bp  = (const float*)d_in[21];

  u16* wsb = (u16*)d_ws;
  u16* wqb   = wsb;                 // merged [1536][512]
  u16* wj1b  = wsb + 786432;
  u16* wj2b  = wsb + 1310720;
  u16* wcib[2] = {wsb + 1572864, wsb + 2359296};
  u16* wpb   = wsb + 3145728;
  u16* wcoT[2] = {wsb + 3407872, wsb + 3670016};
  u16* wfin[2] = {wsb + 3932160, wsb + 4456448};  // [512][1024]
  float* cvecb = (float*)(wsb + 4980736);          // 3072 floats
  const size_t SLOT = 8388608;                     // 16 MB in u16
  u16* base = wsb + 5242880;
  u16* S0 = base;                // x -> HID -> KP1
  u16* OC = base + 1 * SLOT;     // [16384][1024]: y | o  (2 slots)
  u16* S3 = base + 3 * SLOT;     // QKV(S3..S5) -> REL -> CP(S3..S6)
  u16* S4 = base + 4 * SLOT;     // ... -> YKR
  u16* S6 = base + 6 * SLOT;     // VT
  u16* QKV = S3;
  u16* REL = S3;
  u16* CP  = S3;
  u16* YKR = S4;

  dim3 blk(256), gblk(512);
  xcvt_k<<<dim3(8192), blk, 0, stream>>>(x0, x1, S0);
  wcvt_k<<<dim3(3328), blk, 0, stream>>>(Wq, Wkv, Wj1, Wj2, Wci[0], Wci[1],
                                         Wp, wsb);
  tcvt_k<<<dim3(128), blk, 0, stream>>>(Wco[0], Wco[1], wcoT[0], wcoT[1]);
  cvec_k<<<dim3(12), blk, 0, stream>>>(kn, vn, bp, bco[0], bco[1],
                                       wcib[0], wcib[1], wpb, cvecb);
  // Wcomb_s = Wp @ Wco_s -> Wfin_s cols 512-1023
  for (int s = 0; s < 2; s++)
    gemm9_k<0, 0><<<dim3(16), gblk, 0, stream>>>(
        wpb, 512, 512, 512, wcoT[s], wcoT[s], nullptr, nullptr,
        wfin[s] + 512, 1024, 4);

  // qkv projection: [16384][512] @ [1536][512]^T -> QKV
  gemm9_k<0, 0><<<dim3(1536), gblk, 0, stream>>>(
      S0, 512, 512, 512, wqb, wqb, nullptr, nullptr, QKV, 1536, 12);
  vtrans_k<<<dim3(16, 128), blk, 0, stream>>>(QKV, S6);
  attn_k<<<dim3(1024), blk, 0, stream>>>(QKV, S6, OC);   // y -> OC[:,0:512]

  // judger: HID = gelu([y_s|y_other] @ Wj1^T + bj1) -> S0 (x dead)
  gemm9_k<1, 3><<<dim3(512), gblk, 0, stream>>>(
      OC, 1024, 512, 1024, wj1b, wj1b, bj1, bj1, S0, 512, 4);
  // REL logits = HID @ Wj2^T + bj2 -> S3 (QKV dead)
  gemm9_k<0, 0><<<dim3(512), gblk, 0, stream>>>(
      S0, 512, 512, 512, wj2b, wj2b, bj2, bj2, REL, 512, 4);
  // ykr = y * softmax(REL) -> S4
  relmul_k<<<dim3(4096), blk, 0, stream>>>(REL, OC, YKR);
  // kp1 = ykr @ kw^T + bk -> S0 (HID dead)
  gemm9_k<0, 0><<<dim3(512), gblk, 0, stream>>>(
      YKR, 512, 512, 512, wcib[0] + 262144, wcib[1] + 262144,
      bci[0] + 512, bci[1] + 512, S0, 512, 4);
  // merged cross projection -> CP [16384][2048] (4th block: y_other @ vw_s)
  gemm9_k<0, 4><<<dim3(2048), gblk, 0, stream>>>(
      OC, 1024, 512, 512, wcib[0], wcib[1], bci[0], bci[1], CP, 2048, 16);

  twokey3_k<<<dim3(4096), blk, 0, stream>>>(CP, S0, cvecb, OC);

  // out = [y|o] @ [Wp | Wp@Wco_s]^T + bcomb_s  (f32)
  gemm9_k<3, 0><<<dim3(512), gblk, 0, stream>>>(
      OC, 1024, 1024, 1024, wfin[0], wfin[1], cvecb + 2048, cvecb + 2560,
      d_out, 512, 4);
}